// Round 4
// baseline (956.674 us; speedup 1.0000x reference)
//
#include <hip/hip_runtime.h>

#define NUM_CN   25000
#define NUM_VN   50000
#define NUM_E    200000
#define D_EMBED  16
#define D_HIDDEN 32
#define D_MSG    16
#define BATCH    16

// ---------------------------------------------------------------------------
// Workspace layout (int units):
#define WS_IDS_X   0           // 200000   (stores FROM node ids, CSR order)
#define WS_IDS_Z   200000      // 200000
#define WS_OFF_X   400000      // 50001
#define WS_OFF_Z   450001      // 50001
#define WS_CNT_X   500002      // 50000
#define WS_CNT_Z   550002      // 50000
#define WS_CUR_X   600002      // 50000  -> reused as ORDER after fill
#define WS_CUR_Z   650002      // 50000  -> reused as BITS_X/BITS_Z after fill
#define WS_INCL_X  700002      // 51200
#define WS_INCL_Z  751202      // 51200
#define WS_PSUM    802402      // 128    -> reused as degree-sort histogram
#define WS_BASE    802530      // 128    -> reused as degree-sort bases
#define WS_A1X     802816      // 6400000 ints = 25.6 MB bf16
#define WS_A1Z     7202816     // 6400000
#define WS_END_A1  13602816    // 54.41 MB total if A1 path used
#define SCAN_CHUNKS 49

__global__ __launch_bounds__(256) void hist_kernel(
    const int* __restrict__ ti_x, const int* __restrict__ ti_z,
    int* __restrict__ cnt_x, int* __restrict__ cnt_z)
{
    int e = blockIdx.x * 256 + threadIdx.x;
    if (e >= NUM_E) return;
    atomicAdd(&cnt_x[ti_x[e]], 1);
    atomicAdd(&cnt_z[ti_z[e]], 1);
}

__global__ __launch_bounds__(1024) void scan1_kernel(
    const int* __restrict__ cnt_x, const int* __restrict__ cnt_z,
    int* __restrict__ incl_x, int* __restrict__ incl_z,
    int* __restrict__ psum)
{
    __shared__ int s[1024];
    const int ch  = blockIdx.y;
    const int blk = blockIdx.x;
    const int t   = threadIdx.x;
    const int gid = blk * 1024 + t;
    const int* cnt  = ch ? cnt_z  : cnt_x;
    int*       incl = ch ? incl_z : incl_x;
    int v = (gid < NUM_VN) ? cnt[gid] : 0;
    s[t] = v;
    __syncthreads();
#pragma unroll
    for (int d = 1; d < 1024; d <<= 1) {
        int x = 0;
        if (t >= d) x = s[t - d];
        __syncthreads();
        if (t >= d) s[t] += x;
        __syncthreads();
    }
    incl[gid] = s[t];
    if (t == 1023) psum[ch * 64 + blk] = s[1023];
}

__global__ void scan2_kernel(const int* __restrict__ psum, int* __restrict__ base)
{
    int ch = threadIdx.x;
    if (ch >= 2) return;
    int run = 0;
    for (int i = 0; i < SCAN_CHUNKS; ++i) {
        base[ch * 64 + i] = run;
        run += psum[ch * 64 + i];
    }
}

__global__ __launch_bounds__(1024) void scan3_kernel(
    const int* __restrict__ cnt_x, const int* __restrict__ cnt_z,
    const int* __restrict__ incl_x, const int* __restrict__ incl_z,
    const int* __restrict__ base,
    int* __restrict__ off_x, int* __restrict__ off_z,
    int* __restrict__ cur_x, int* __restrict__ cur_z)
{
    const int ch  = blockIdx.y;
    const int blk = blockIdx.x;
    const int t   = threadIdx.x;
    const int i   = blk * 1024 + t;
    if (i >= NUM_VN) return;
    const int* cnt  = ch ? cnt_z  : cnt_x;
    const int* incl = ch ? incl_z : incl_x;
    int*       off  = ch ? off_z  : off_x;
    int*       cur  = ch ? cur_z  : cur_x;
    int bs = base[ch * 64 + blk];
    int iv = incl[i];
    off[i + 1] = bs + iv;
    cur[i]     = bs + iv - cnt[i];
    if (i == 0) off[0] = 0;
}

__global__ __launch_bounds__(256) void fill_kernel(
    const int* __restrict__ ti_x, const int* __restrict__ ti_z,
    const int* __restrict__ fi_x, const int* __restrict__ fi_z,
    int* __restrict__ cur_x, int* __restrict__ cur_z,
    int* __restrict__ ids_x, int* __restrict__ ids_z)
{
    int e = blockIdx.x * 256 + threadIdx.x;
    if (e >= NUM_E) return;
    int px = atomicAdd(&cur_x[ti_x[e]], 1);
    ids_x[px] = fi_x[e];
    int pz = atomicAdd(&cur_z[ti_z[e]], 1);
    ids_z[pz] = fi_z[e];
}

// syn bitmask: bits[cn] bit b = syn[b,cn]. Coalesced along cn per b-pass.
__global__ __launch_bounds__(256) void pack_bits_kernel(
    const int* __restrict__ syn_x, const int* __restrict__ syn_z,
    unsigned* __restrict__ bits_x, unsigned* __restrict__ bits_z)
{
    int cn = blockIdx.x * 256 + threadIdx.x;
    if (cn >= NUM_CN) return;
    unsigned wx = 0, wz = 0;
#pragma unroll
    for (int b = 0; b < BATCH; ++b) {
        wx |= (unsigned)(syn_x[b * NUM_CN + cn] & 1) << b;
        wz |= (unsigned)(syn_z[b * NUM_CN + cn] & 1) << b;
    }
    bits_x[cn] = wx;
    bits_z[cn] = wz;
}

// degree sort (descending): similar-degree nodes land in the same wave.
__global__ __launch_bounds__(256) void dsort_count_kernel(
    const int* __restrict__ off_x, const int* __restrict__ off_z,
    int* __restrict__ dcnt)
{
    int n = blockIdx.x * 256 + threadIdx.x;
    if (n >= NUM_VN) return;
    int deg = (off_x[n + 1] - off_x[n]) + (off_z[n + 1] - off_z[n]);
    int bin = 63 - min(deg, 63);
    atomicAdd(&dcnt[bin], 1);
}

__global__ void dsort_scan_kernel(const int* __restrict__ dcnt, int* __restrict__ dbase)
{
    if (threadIdx.x != 0) return;
    int run = 0;
    for (int i = 0; i < 64; ++i) { dbase[i] = run; run += dcnt[i]; }
}

__global__ __launch_bounds__(256) void dsort_place_kernel(
    const int* __restrict__ off_x, const int* __restrict__ off_z,
    int* __restrict__ dbase, int* __restrict__ order)
{
    int n = blockIdx.x * 256 + threadIdx.x;
    if (n >= NUM_VN) return;
    int deg = (off_x[n + 1] - off_x[n]) + (off_z[n + 1] - off_z[n]);
    int bin = 63 - min(deg, 63);
    int pos = atomicAdd(&dbase[bin], 1);
    order[pos] = n;
}

// ---------------------------------------------------------------------------
// a1[ch][cn][b][32] = h_from[b,cn,:] @ W1[0:16,:]  bf16 lane-interleaved:
// per-cn block of 64 uint4; lane b's p-th uint4 at block + p*16 + b.
__device__ __forceinline__ unsigned pack_bf16(float a, float b) {
    unsigned ua = __float_as_uint(a); ua += 0x7fff + ((ua >> 16) & 1);
    unsigned ub = __float_as_uint(b); ub += 0x7fff + ((ub >> 16) & 1);
    return (ua >> 16) | (ub & 0xffff0000u);
}

__global__ __launch_bounds__(256) void a1_kernel(
    const float* __restrict__ h_from_x, const float* __restrict__ h_from_z,
    const float* __restrict__ Wx1, const float* __restrict__ Wz1,
    uint4* __restrict__ a1x, uint4* __restrict__ a1z)
{
    int t = blockIdx.x * 256 + threadIdx.x;
    if (t >= NUM_CN * BATCH) return;
    const int ch = blockIdx.y;
    const int b  = t & 15;
    const int cn = t >> 4;
    const float* hsrc = (ch ? h_from_z : h_from_x) + ((size_t)b * NUM_CN + cn) * D_EMBED;
    const float* W1   = ch ? Wz1 : Wx1;
    uint4* dst = (ch ? a1z : a1x) + (size_t)cn * 64;

    float hf[D_EMBED];
#pragma unroll
    for (int i = 0; i < 4; ++i) {
        float4 v = ((const float4*)hsrc)[i];
        hf[4 * i + 0] = v.x; hf[4 * i + 1] = v.y;
        hf[4 * i + 2] = v.z; hf[4 * i + 3] = v.w;
    }
    float a[D_HIDDEN];
#pragma unroll
    for (int j = 0; j < D_HIDDEN; ++j) a[j] = 0.0f;
#pragma unroll
    for (int i = 0; i < D_EMBED; ++i) {
        const float fi = hf[i];
#pragma unroll
        for (int j = 0; j < D_HIDDEN; ++j)
            a[j] = fmaf(fi, W1[i * D_HIDDEN + j], a[j]);
    }
    unsigned u[16];
#pragma unroll
    for (int j = 0; j < 16; ++j) u[j] = pack_bf16(a[2 * j], a[2 * j + 1]);
#pragma unroll
    for (int p = 0; p < 4; ++p) {
        uint4 q;
        q.x = u[4 * p + 0]; q.y = u[4 * p + 1];
        q.z = u[4 * p + 2]; q.w = u[4 * p + 3];
        dst[p * 16 + b] = q;
    }
}

// ---------------------------------------------------------------------------
__device__ __forceinline__ void compute_hid0(
    const float ht[D_EMBED], const float* __restrict__ W1, float2 hid0[16])
{
#pragma unroll
    for (int p = 0; p < 16; ++p) { hid0[p].x = 0.0f; hid0[p].y = 0.0f; }
#pragma unroll
    for (int i = 0; i < D_EMBED; ++i) {
        const float hi = ht[i];
        const float* w = W1 + (D_EMBED + i) * D_HIDDEN;
#pragma unroll
        for (int p = 0; p < 16; ++p) {
            hid0[p].x = fmaf(hi, w[2 * p],     hid0[p].x);
            hid0[p].y = fmaf(hi, w[2 * p + 1], hid0[p].y);
        }
    }
}

// depth-2 pipelined edge accumulation over the A1 table.
__device__ __forceinline__ void accum_a1(
    int n, int b,
    const int* __restrict__ off, const int* __restrict__ ids,
    const unsigned* __restrict__ bits,
    const uint4* __restrict__ a1,
    const float2 hid0[16], float2 hacc[16])
{
#pragma unroll
    for (int p = 0; p < 16; ++p) { hacc[p].x = 0.0f; hacc[p].y = 0.0f; }
    const int ks  = off[n];
    const int cnt = off[n + 1] - ks;
    if (cnt <= 0) return;
    const int* idp = ids + ks;

    uint4 q0a = {0,0,0,0}, q0b = q0a, q0c = q0a, q0d = q0a;
    uint4 q1a = q0a, q1b = q0a, q1c = q0a, q1d = q0a;

    int fr0 = idp[0];
    unsigned sy0 = (bits[fr0] >> b) & 1u;
    if (sy0) {
        const uint4* pa = a1 + (size_t)fr0 * 64 + b;
        q0a = pa[0]; q0b = pa[16]; q0c = pa[32]; q0d = pa[48];
    }
    int fr1 = 0; unsigned sy1 = 0;
    if (cnt > 1) { fr1 = idp[1]; sy1 = (bits[fr1] >> b) & 1u; }

    for (int k = 0; k < cnt; ++k) {
        // meta prefetch for k+2
        int fr2 = 0; unsigned sy2 = 0;
        if (k + 2 < cnt) { fr2 = idp[k + 2]; sy2 = (bits[fr2] >> b) & 1u; }
        // a1 prefetch for k+1
        if (sy1) {
            const uint4* pa = a1 + (size_t)fr1 * 64 + b;
            q1a = pa[0]; q1b = pa[16]; q1c = pa[32]; q1d = pa[48];
        }
        // accumulate edge k
        if (sy0) {
            unsigned uu[16] = {q0a.x, q0a.y, q0a.z, q0a.w,
                               q0b.x, q0b.y, q0b.z, q0b.w,
                               q0c.x, q0c.y, q0c.z, q0c.w,
                               q0d.x, q0d.y, q0d.z, q0d.w};
#pragma unroll
            for (int p = 0; p < 16; ++p) {
                float lo = __uint_as_float(uu[p] << 16);
                float hi = __uint_as_float(uu[p] & 0xffff0000u);
                hacc[p].x += fmaxf(hid0[p].x + lo, 0.0f);
                hacc[p].y += fmaxf(hid0[p].y + hi, 0.0f);
            }
        }
        sy0 = sy1; q0a = q1a; q0b = q1b; q0c = q1c; q0d = q1d;
        fr1 = fr2; sy1 = sy2;
    }
}

// fallback (no-A1 workspace): inline W1 per edge.
__device__ __forceinline__ void accum_inline(
    int n, int b,
    const int* __restrict__ off, const int* __restrict__ ids,
    const unsigned* __restrict__ bits,
    const float* __restrict__ h_from, const float* __restrict__ W1,
    const float2 hid0[16], float2 hacc[16])
{
#pragma unroll
    for (int p = 0; p < 16; ++p) { hacc[p].x = 0.0f; hacc[p].y = 0.0f; }
    const int ks = off[n], ke = off[n + 1];
    for (int k = ks; k < ke; ++k) {
        const int from = ids[k];
        if (((bits[from] >> b) & 1u) == 0u) continue;
        const float* pf = h_from + ((size_t)b * NUM_CN + from) * D_EMBED;
        float hf[D_EMBED];
#pragma unroll
        for (int i = 0; i < 4; ++i) {
            float4 v = ((const float4*)pf)[i];
            hf[4 * i + 0] = v.x; hf[4 * i + 1] = v.y;
            hf[4 * i + 2] = v.z; hf[4 * i + 3] = v.w;
        }
        float2 hid[16];
#pragma unroll
        for (int p = 0; p < 16; ++p) hid[p] = hid0[p];
#pragma unroll
        for (int i = 0; i < D_EMBED; ++i) {
            const float fi = hf[i];
            const float* w = W1 + i * D_HIDDEN;
#pragma unroll
            for (int p = 0; p < 16; ++p) {
                hid[p].x = fmaf(fi, w[2 * p],     hid[p].x);
                hid[p].y = fmaf(fi, w[2 * p + 1], hid[p].y);
            }
        }
#pragma unroll
        for (int p = 0; p < 16; ++p) {
            hacc[p].x += fmaxf(hid[p].x, 0.0f);
            hacc[p].y += fmaxf(hid[p].y, 0.0f);
        }
    }
}

__device__ __forceinline__ void apply_w2(
    const float2 hacc[16], const float* __restrict__ W2, float m[D_MSG])
{
#pragma unroll
    for (int k = 0; k < D_MSG; ++k) m[k] = 0.0f;
#pragma unroll
    for (int p = 0; p < 16; ++p) {
        const float h0 = hacc[p].x, h1 = hacc[p].y;
        const float* w0 = W2 + (2 * p) * D_MSG;
        const float* w1 = W2 + (2 * p + 1) * D_MSG;
#pragma unroll
        for (int k = 0; k < D_MSG; ++k)
            m[k] = fmaf(h0, w0[k], fmaf(h1, w1[k], m[k]));
    }
}

template <int USE_A1>
__global__ __launch_bounds__(256) void fused_gather_kernel(
    const float* __restrict__ h_from_x, const float* __restrict__ h_from_z,
    const float* __restrict__ h_to,
    const unsigned* __restrict__ bits_x, const unsigned* __restrict__ bits_z,
    const int* __restrict__ off_x, const int* __restrict__ ids_x,
    const int* __restrict__ off_z, const int* __restrict__ ids_z,
    const int* __restrict__ order,
    const uint4* __restrict__ a1x, const uint4* __restrict__ a1z,
    const float* __restrict__ Wx1, const float* __restrict__ Wx2,
    const float* __restrict__ Wz1, const float* __restrict__ Wz2,
    const float* __restrict__ We1, const float* __restrict__ We2,
    float* __restrict__ out)
{
    const int t = blockIdx.x * 256 + threadIdx.x;
    if (t >= NUM_VN * BATCH) return;
    const int b = t & (BATCH - 1);
    const int n = order[t >> 4];

    const size_t base_to = ((size_t)b * NUM_VN + n) * D_EMBED;

    float ht[D_EMBED];
#pragma unroll
    for (int i = 0; i < 4; ++i) {
        float4 v = ((const float4*)(h_to + base_to))[i];
        ht[4 * i + 0] = v.x; ht[4 * i + 1] = v.y;
        ht[4 * i + 2] = v.z; ht[4 * i + 3] = v.w;
    }

    float2 hid0[16];
    float2 hacc[16];
    float mx[D_MSG], mz[D_MSG];

    compute_hid0(ht, Wx1, hid0);
    if (USE_A1)
        accum_a1(n, b, off_x, ids_x, bits_x, a1x, hid0, hacc);
    else
        accum_inline(n, b, off_x, ids_x, bits_x, h_from_x, Wx1, hid0, hacc);
    apply_w2(hacc, Wx2, mx);

    compute_hid0(ht, Wz1, hid0);
    if (USE_A1)
        accum_a1(n, b, off_z, ids_z, bits_z, a1z, hid0, hacc);
    else
        accum_inline(n, b, off_z, ids_z, bits_z, h_from_z, Wz1, hid0, hacc);
    apply_w2(hacc, Wz2, mz);

    // node MLP: [mx | mz | ht](48) -> 32 relu -> 16
    float hid[D_HIDDEN];
#pragma unroll
    for (int j = 0; j < D_HIDDEN; ++j) hid[j] = 0.0f;
#pragma unroll
    for (int i = 0; i < D_MSG; ++i) {
        const float fi = mx[i];
#pragma unroll
        for (int j = 0; j < D_HIDDEN; ++j)
            hid[j] = fmaf(fi, We1[i * D_HIDDEN + j], hid[j]);
    }
#pragma unroll
    for (int i = 0; i < D_MSG; ++i) {
        const float fi = mz[i];
#pragma unroll
        for (int j = 0; j < D_HIDDEN; ++j)
            hid[j] = fmaf(fi, We1[(D_MSG + i) * D_HIDDEN + j], hid[j]);
    }
#pragma unroll
    for (int i = 0; i < D_EMBED; ++i) {
        const float fi = ht[i];
#pragma unroll
        for (int j = 0; j < D_HIDDEN; ++j)
            hid[j] = fmaf(fi, We1[(2 * D_MSG + i) * D_HIDDEN + j], hid[j]);
    }
#pragma unroll
    for (int j = 0; j < D_HIDDEN; ++j) hid[j] = fmaxf(hid[j], 0.0f);

    float o[D_EMBED];
#pragma unroll
    for (int k = 0; k < D_EMBED; ++k) o[k] = 0.0f;
#pragma unroll
    for (int j = 0; j < D_HIDDEN; ++j) {
        const float hj = hid[j];
#pragma unroll
        for (int k = 0; k < D_EMBED; ++k)
            o[k] = fmaf(hj, We2[j * D_EMBED + k], o[k]);
    }

#pragma unroll
    for (int i = 0; i < 4; ++i) {
        float4 v;
        v.x = o[4 * i + 0]; v.y = o[4 * i + 1];
        v.z = o[4 * i + 2]; v.w = o[4 * i + 3];
        ((float4*)(out + base_to))[i] = v;
    }
}

// ---------------------------------------------------------------------------
extern "C" void kernel_launch(void* const* d_in, const int* in_sizes, int n_in,
                              void* d_out, int out_size, void* d_ws, size_t ws_size,
                              hipStream_t stream) {
    const float* h_from_x = (const float*)d_in[0];
    const float* h_from_z = (const float*)d_in[1];
    const float* h_to     = (const float*)d_in[2];
    const int*   syn_x    = (const int*)d_in[3];
    const int*   syn_z    = (const int*)d_in[4];
    const int*   fi_x     = (const int*)d_in[5];
    const int*   ti_x     = (const int*)d_in[6];
    const int*   fi_z     = (const int*)d_in[7];
    const int*   ti_z     = (const int*)d_in[8];
    const float* Wx1      = (const float*)d_in[9];
    const float* Wx2      = (const float*)d_in[10];
    const float* Wz1      = (const float*)d_in[11];
    const float* Wz2      = (const float*)d_in[12];
    const float* We1      = (const float*)d_in[13];
    const float* We2      = (const float*)d_in[14];

    int* ws = (int*)d_ws;
    int* ids_x  = ws + WS_IDS_X;
    int* ids_z  = ws + WS_IDS_Z;
    int* off_x  = ws + WS_OFF_X;
    int* off_z  = ws + WS_OFF_Z;
    int* cnt_x  = ws + WS_CNT_X;
    int* cnt_z  = ws + WS_CNT_Z;
    int* cur_x  = ws + WS_CUR_X;
    int* cur_z  = ws + WS_CUR_Z;
    int* incl_x = ws + WS_INCL_X;
    int* incl_z = ws + WS_INCL_Z;
    int* psum   = ws + WS_PSUM;
    int* base   = ws + WS_BASE;
    uint4* a1x  = (uint4*)(ws + WS_A1X);
    uint4* a1z  = (uint4*)(ws + WS_A1Z);

    // region reuse after fill_kernel: cur_x -> order, cur_z -> bit masks,
    // psum -> degree histogram, base -> degree-sort bases.
    int*      order  = cur_x;
    unsigned* bits_x = (unsigned*)cur_z;
    unsigned* bits_z = (unsigned*)cur_z + NUM_CN;
    int*      dcnt   = psum;
    int*      dbase  = base;

    const bool use_a1 = ws_size >= (size_t)WS_END_A1 * sizeof(int);

    hipMemsetAsync(cnt_x, 0, 2 * NUM_VN * sizeof(int), stream);

    hist_kernel<<<dim3((NUM_E + 255) / 256), dim3(256), 0, stream>>>(
        ti_x, ti_z, cnt_x, cnt_z);
    scan1_kernel<<<dim3(SCAN_CHUNKS, 2), dim3(1024), 0, stream>>>(
        cnt_x, cnt_z, incl_x, incl_z, psum);
    scan2_kernel<<<dim3(1), dim3(64), 0, stream>>>(psum, base);
    scan3_kernel<<<dim3(SCAN_CHUNKS, 2), dim3(1024), 0, stream>>>(
        cnt_x, cnt_z, incl_x, incl_z, base, off_x, off_z, cur_x, cur_z);
    fill_kernel<<<dim3((NUM_E + 255) / 256), dim3(256), 0, stream>>>(
        ti_x, ti_z, fi_x, fi_z, cur_x, cur_z, ids_x, ids_z);

    // cur_* now dead -> safe to overwrite with bits/order
    pack_bits_kernel<<<dim3((NUM_CN + 255) / 256), dim3(256), 0, stream>>>(
        syn_x, syn_z, bits_x, bits_z);

    hipMemsetAsync(dcnt, 0, 64 * sizeof(int), stream);   // psum dead after scan2
    dsort_count_kernel<<<dim3((NUM_VN + 255) / 256), dim3(256), 0, stream>>>(
        off_x, off_z, dcnt);
    dsort_scan_kernel<<<dim3(1), dim3(64), 0, stream>>>(dcnt, dbase);
    dsort_place_kernel<<<dim3((NUM_VN + 255) / 256), dim3(256), 0, stream>>>(
        off_x, off_z, dbase, order);

    if (use_a1) {
        a1_kernel<<<dim3((NUM_CN * BATCH + 255) / 256, 2), dim3(256), 0, stream>>>(
            h_from_x, h_from_z, Wx1, Wz1, a1x, a1z);
        fused_gather_kernel<1><<<dim3((NUM_VN * BATCH) / 256), dim3(256), 0, stream>>>(
            h_from_x, h_from_z, h_to, bits_x, bits_z,
            off_x, ids_x, off_z, ids_z, order, a1x, a1z,
            Wx1, Wx2, Wz1, Wz2, We1, We2, (float*)d_out);
    } else {
        fused_gather_kernel<0><<<dim3((NUM_VN * BATCH) / 256), dim3(256), 0, stream>>>(
            h_from_x, h_from_z, h_to, bits_x, bits_z,
            off_x, ids_x, off_z, ids_z, order, a1x, a1z,
            Wx1, Wx2, Wz1, Wz2, We1, We2, (float*)d_out);
    }
}

// Round 5
// 419.447 us; speedup vs baseline: 2.2808x; 2.2808x over previous
//
#include <hip/hip_runtime.h>

#define NUM_CN   25000
#define NUM_VN   50000
#define NUM_E    200000
#define D_EMBED  16
#define D_HIDDEN 32
#define D_MSG    16
#define BATCH    16

// ---------------------------------------------------------------------------
// Workspace layout (int units) — 54.41 MB total (proven available in R2-R4):
#define WS_IDS_X   0           // 200000  (stores FROM node ids, CSR order)
#define WS_IDS_Z   200000      // 200000
#define WS_OFF_X   400000      // 50001
#define WS_OFF_Z   450001      // 50001
#define WS_CNT_X   500002      // 50000
#define WS_CNT_Z   550002      // 50000
#define WS_CUR_X   600002      // 50000 -> bits_x after fill
#define WS_CUR_Z   650002      // 50000 -> bits_z after fill
#define WS_INCL_X  700002      // 51200
#define WS_INCL_Z  751202      // 51200
#define WS_PSUM    802402      // 128
#define WS_BASE    802530      // 128
#define WS_A1X     802816      // 6400000 ints = 25.6 MB bf16
#define WS_A1Z     7202816     // 6400000
#define SCAN_CHUNKS 49

__global__ __launch_bounds__(256) void hist_kernel(
    const int* __restrict__ ti_x, const int* __restrict__ ti_z,
    int* __restrict__ cnt_x, int* __restrict__ cnt_z)
{
    int e = blockIdx.x * 256 + threadIdx.x;
    if (e >= NUM_E) return;
    atomicAdd(&cnt_x[ti_x[e]], 1);
    atomicAdd(&cnt_z[ti_z[e]], 1);
}

__global__ __launch_bounds__(1024) void scan1_kernel(
    const int* __restrict__ cnt_x, const int* __restrict__ cnt_z,
    int* __restrict__ incl_x, int* __restrict__ incl_z,
    int* __restrict__ psum)
{
    __shared__ int s[1024];
    const int ch  = blockIdx.y;
    const int blk = blockIdx.x;
    const int t   = threadIdx.x;
    const int gid = blk * 1024 + t;
    const int* cnt  = ch ? cnt_z  : cnt_x;
    int*       incl = ch ? incl_z : incl_x;
    int v = (gid < NUM_VN) ? cnt[gid] : 0;
    s[t] = v;
    __syncthreads();
#pragma unroll
    for (int d = 1; d < 1024; d <<= 1) {
        int x = 0;
        if (t >= d) x = s[t - d];
        __syncthreads();
        if (t >= d) s[t] += x;
        __syncthreads();
    }
    incl[gid] = s[t];
    if (t == 1023) psum[ch * 64 + blk] = s[1023];
}

__global__ void scan2_kernel(const int* __restrict__ psum, int* __restrict__ base)
{
    int ch = threadIdx.x;
    if (ch >= 2) return;
    int run = 0;
    for (int i = 0; i < SCAN_CHUNKS; ++i) {
        base[ch * 64 + i] = run;
        run += psum[ch * 64 + i];
    }
}

__global__ __launch_bounds__(1024) void scan3_kernel(
    const int* __restrict__ cnt_x, const int* __restrict__ cnt_z,
    const int* __restrict__ incl_x, const int* __restrict__ incl_z,
    const int* __restrict__ base,
    int* __restrict__ off_x, int* __restrict__ off_z,
    int* __restrict__ cur_x, int* __restrict__ cur_z)
{
    const int ch  = blockIdx.y;
    const int blk = blockIdx.x;
    const int t   = threadIdx.x;
    const int i   = blk * 1024 + t;
    if (i >= NUM_VN) return;
    const int* cnt  = ch ? cnt_z  : cnt_x;
    const int* incl = ch ? incl_z : incl_x;
    int*       off  = ch ? off_z  : off_x;
    int*       cur  = ch ? cur_z  : cur_x;
    int bs = base[ch * 64 + blk];
    int iv = incl[i];
    off[i + 1] = bs + iv;
    cur[i]     = bs + iv - cnt[i];
    if (i == 0) off[0] = 0;
}

// fill: CSR slot stores the FROM node id directly.
__global__ __launch_bounds__(256) void fill_kernel(
    const int* __restrict__ ti_x, const int* __restrict__ ti_z,
    const int* __restrict__ fi_x, const int* __restrict__ fi_z,
    int* __restrict__ cur_x, int* __restrict__ cur_z,
    int* __restrict__ ids_x, int* __restrict__ ids_z)
{
    int e = blockIdx.x * 256 + threadIdx.x;
    if (e >= NUM_E) return;
    int px = atomicAdd(&cur_x[ti_x[e]], 1);
    ids_x[px] = fi_x[e];
    int pz = atomicAdd(&cur_z[ti_z[e]], 1);
    ids_z[pz] = fi_z[e];
}

// syn bitmask: bits[cn] bit b = syn[b,cn]. Runs AFTER fill (targets dead cur_*).
__global__ __launch_bounds__(256) void pack_bits_kernel(
    const int* __restrict__ syn_x, const int* __restrict__ syn_z,
    unsigned* __restrict__ bits_x, unsigned* __restrict__ bits_z)
{
    int cn = blockIdx.x * 256 + threadIdx.x;
    if (cn >= NUM_CN) return;
    unsigned wx = 0, wz = 0;
#pragma unroll
    for (int b = 0; b < BATCH; ++b) {
        wx |= (unsigned)(syn_x[b * NUM_CN + cn] & 1) << b;
        wz |= (unsigned)(syn_z[b * NUM_CN + cn] & 1) << b;
    }
    bits_x[cn] = wx;
    bits_z[cn] = wz;
}

// ---------------------------------------------------------------------------
__device__ __forceinline__ unsigned pack_bf16(float a, float b) {
    unsigned ua = __float_as_uint(a); ua += 0x7fff + ((ua >> 16) & 1);
    unsigned ub = __float_as_uint(b); ub += 0x7fff + ((ub >> 16) & 1);
    return (ua >> 16) | (ub & 0xffff0000u);
}

// a1[ch][cn][b][32] = h_from[b,cn,:] @ W1[0:16,:]  bf16 lane-interleaved:
// per-cn block of 64 uint4; lane b's p-th uint4 at block + p*16 + b, so the
// 16 batch-lanes of a node-group read contiguous 256 B per instruction.
__global__ __launch_bounds__(256) void a1_kernel(
    const float* __restrict__ h_from_x, const float* __restrict__ h_from_z,
    const float* __restrict__ Wx1, const float* __restrict__ Wz1,
    uint4* __restrict__ a1x, uint4* __restrict__ a1z)
{
    int t = blockIdx.x * 256 + threadIdx.x;
    if (t >= NUM_CN * BATCH) return;
    const int ch = blockIdx.y;
    const int b  = t & 15;
    const int cn = t >> 4;
    const float* hsrc = (ch ? h_from_z : h_from_x) + ((size_t)b * NUM_CN + cn) * D_EMBED;
    const float* W1   = ch ? Wz1 : Wx1;
    uint4* dst = (ch ? a1z : a1x) + (size_t)cn * 64;

    float hf[D_EMBED];
#pragma unroll
    for (int i = 0; i < 4; ++i) {
        float4 v = ((const float4*)hsrc)[i];
        hf[4 * i + 0] = v.x; hf[4 * i + 1] = v.y;
        hf[4 * i + 2] = v.z; hf[4 * i + 3] = v.w;
    }
    float a[D_HIDDEN];
#pragma unroll
    for (int j = 0; j < D_HIDDEN; ++j) a[j] = 0.0f;
#pragma unroll
    for (int i = 0; i < D_EMBED; ++i) {
        const float fi = hf[i];
#pragma unroll
        for (int j = 0; j < D_HIDDEN; ++j)
            a[j] = fmaf(fi, W1[i * D_HIDDEN + j], a[j]);
    }
    unsigned u[16];
#pragma unroll
    for (int j = 0; j < 16; ++j) u[j] = pack_bf16(a[2 * j], a[2 * j + 1]);
#pragma unroll
    for (int p = 0; p < 4; ++p) {
        uint4 q;
        q.x = u[4 * p + 0]; q.y = u[4 * p + 1];
        q.z = u[4 * p + 2]; q.w = u[4 * p + 3];
        dst[p * 16 + b] = q;
    }
}

// ---------------------------------------------------------------------------
// One channel: a2 = ht @ W1[16:32]; hacc = sum_e fm * relu(a1[from] + a2);
// m = hacc @ W2, packed to 8 bf16-pair words. Branchless: bits and a1 loads
// are independent (one-hop chain from ids[k]); mask applied as an FMA.
__device__ __forceinline__ void channel_accum(
    const float* __restrict__ h_to_slot, int n, int b,
    const int* __restrict__ off, const int* __restrict__ ids,
    const unsigned* __restrict__ bits,
    const uint4* __restrict__ a1,
    const float* __restrict__ W1, const float* __restrict__ W2,
    unsigned* __restrict__ um)
{
    // reload ht per channel: 4 cache-hit loads < 16 live registers
    float ht[D_EMBED];
#pragma unroll
    for (int i = 0; i < 4; ++i) {
        float4 v = ((const float4*)h_to_slot)[i];
        ht[4 * i + 0] = v.x; ht[4 * i + 1] = v.y;
        ht[4 * i + 2] = v.z; ht[4 * i + 3] = v.w;
    }
    float2 a2[16];
#pragma unroll
    for (int p = 0; p < 16; ++p) { a2[p].x = 0.0f; a2[p].y = 0.0f; }
#pragma unroll
    for (int i = 0; i < D_EMBED; ++i) {
        const float hi = ht[i];
        const float* w = W1 + (D_EMBED + i) * D_HIDDEN;
#pragma unroll
        for (int p = 0; p < 16; ++p) {
            a2[p].x = fmaf(hi, w[2 * p],     a2[p].x);
            a2[p].y = fmaf(hi, w[2 * p + 1], a2[p].y);
        }
    }

    float2 hacc[16];
#pragma unroll
    for (int p = 0; p < 16; ++p) { hacc[p].x = 0.0f; hacc[p].y = 0.0f; }

    const int ks = off[n], ke = off[n + 1];
    for (int k = ks; k < ke; ++k) {
        const int from = ids[k];
        const unsigned mw = bits[from];                  // independent of a1 loads
        const uint4* pa = a1 + (size_t)from * 64 + b;
        uint4 q0 = pa[0], q1 = pa[16], q2 = pa[32], q3 = pa[48];
        const float fm = (float)((mw >> b) & 1u);
        unsigned uu[16] = {q0.x, q0.y, q0.z, q0.w,
                           q1.x, q1.y, q1.z, q1.w,
                           q2.x, q2.y, q2.z, q2.w,
                           q3.x, q3.y, q3.z, q3.w};
#pragma unroll
        for (int p = 0; p < 16; ++p) {
            float lo = __uint_as_float(uu[p] << 16);
            float hi = __uint_as_float(uu[p] & 0xffff0000u);
            hacc[p].x = fmaf(fm, fmaxf(a2[p].x + lo, 0.0f), hacc[p].x);
            hacc[p].y = fmaf(fm, fmaxf(a2[p].y + hi, 0.0f), hacc[p].y);
        }
    }

    float m[D_MSG];
#pragma unroll
    for (int j = 0; j < D_MSG; ++j) m[j] = 0.0f;
#pragma unroll
    for (int p = 0; p < 16; ++p) {
        const float h0 = hacc[p].x, h1 = hacc[p].y;
        const float* w0 = W2 + (2 * p) * D_MSG;
        const float* w1 = W2 + (2 * p + 1) * D_MSG;
#pragma unroll
        for (int j = 0; j < D_MSG; ++j)
            m[j] = fmaf(h0, w0[j], fmaf(h1, w1[j], m[j]));
    }
#pragma unroll
    for (int j = 0; j < 8; ++j) um[j] = pack_bf16(m[2 * j], m[2 * j + 1]);
}

// gather: thread=(n,b); writes packed bf16 {mx|mz} (64 B) into the thread's
// OWN final-output slot in d_out (node kernel reads then overwrites it).
__global__ __launch_bounds__(256) void gather_kernel(
    const float* __restrict__ h_to,
    const unsigned* __restrict__ bits_x, const unsigned* __restrict__ bits_z,
    const int* __restrict__ off_x, const int* __restrict__ ids_x,
    const int* __restrict__ off_z, const int* __restrict__ ids_z,
    const uint4* __restrict__ a1x, const uint4* __restrict__ a1z,
    const float* __restrict__ Wx1, const float* __restrict__ Wx2,
    const float* __restrict__ Wz1, const float* __restrict__ Wz2,
    uint4* __restrict__ out_m)
{
    const int t = blockIdx.x * 256 + threadIdx.x;
    if (t >= NUM_VN * BATCH) return;
    const int b = t & (BATCH - 1);
    const int n = t >> 4;
    const size_t slot = (size_t)b * NUM_VN + n;
    const float* ht_slot = h_to + slot * D_EMBED;

    unsigned um[16];
    channel_accum(ht_slot, n, b, off_x, ids_x, bits_x, a1x, Wx1, Wx2, um);
    channel_accum(ht_slot, n, b, off_z, ids_z, bits_z, a1z, Wz1, Wz2, um + 8);

    uint4* dst = out_m + slot * 4;
#pragma unroll
    for (int p = 0; p < 4; ++p) {
        uint4 q;
        q.x = um[4 * p + 0]; q.y = um[4 * p + 1];
        q.z = um[4 * p + 2]; q.w = um[4 * p + 3];
        dst[p] = q;
    }
}

// node MLP: reads its own slot {mx|mz} + h_to, computes 48->32(relu)->16,
// overwrites the slot with the final fp32 output. out is NOT __restrict__
// (deliberate read-then-write alias, same thread owns both).
__global__ __launch_bounds__(256) void node_kernel(
    const float* __restrict__ h_to,
    const float* __restrict__ We1, const float* __restrict__ We2,
    float* out)
{
    const int t = blockIdx.x * 256 + threadIdx.x;
    if (t >= NUM_VN * BATCH) return;
    const int b = t & (BATCH - 1);
    const int n = t >> 4;
    const size_t slot = (size_t)b * NUM_VN + n;

    const uint4* pm = (const uint4*)out + slot * 4;
    uint4 q0 = pm[0], q1 = pm[1], q2 = pm[2], q3 = pm[3];
    unsigned uu[16] = {q0.x, q0.y, q0.z, q0.w,
                       q1.x, q1.y, q1.z, q1.w,
                       q2.x, q2.y, q2.z, q2.w,
                       q3.x, q3.y, q3.z, q3.w};
    float f[48];
#pragma unroll
    for (int p = 0; p < 16; ++p) {
        f[2 * p]     = __uint_as_float(uu[p] << 16);
        f[2 * p + 1] = __uint_as_float(uu[p] & 0xffff0000u);
    }
#pragma unroll
    for (int i = 0; i < 4; ++i) {
        float4 v = ((const float4*)(h_to + slot * D_EMBED))[i];
        f[32 + 4 * i + 0] = v.x; f[32 + 4 * i + 1] = v.y;
        f[32 + 4 * i + 2] = v.z; f[32 + 4 * i + 3] = v.w;
    }

    float2 hid[16];
#pragma unroll
    for (int p = 0; p < 16; ++p) { hid[p].x = 0.0f; hid[p].y = 0.0f; }
#pragma unroll
    for (int i = 0; i < 48; ++i) {
        const float fi = f[i];
        const float* w = We1 + i * D_HIDDEN;
#pragma unroll
        for (int p = 0; p < 16; ++p) {
            hid[p].x = fmaf(fi, w[2 * p],     hid[p].x);
            hid[p].y = fmaf(fi, w[2 * p + 1], hid[p].y);
        }
    }
#pragma unroll
    for (int p = 0; p < 16; ++p) {
        hid[p].x = fmaxf(hid[p].x, 0.0f);
        hid[p].y = fmaxf(hid[p].y, 0.0f);
    }

    float o[D_EMBED];
#pragma unroll
    for (int k = 0; k < D_EMBED; ++k) o[k] = 0.0f;
#pragma unroll
    for (int p = 0; p < 16; ++p) {
        const float h0 = hid[p].x, h1 = hid[p].y;
        const float* w0 = We2 + (2 * p) * D_EMBED;
        const float* w1 = We2 + (2 * p + 1) * D_EMBED;
#pragma unroll
        for (int k = 0; k < D_EMBED; ++k)
            o[k] = fmaf(h0, w0[k], fmaf(h1, w1[k], o[k]));
    }

#pragma unroll
    for (int i = 0; i < 4; ++i) {
        float4 v;
        v.x = o[4 * i + 0]; v.y = o[4 * i + 1];
        v.z = o[4 * i + 2]; v.w = o[4 * i + 3];
        ((float4*)(out + slot * D_EMBED))[i] = v;
    }
}

// ---------------------------------------------------------------------------
extern "C" void kernel_launch(void* const* d_in, const int* in_sizes, int n_in,
                              void* d_out, int out_size, void* d_ws, size_t ws_size,
                              hipStream_t stream) {
    const float* h_from_x = (const float*)d_in[0];
    const float* h_from_z = (const float*)d_in[1];
    const float* h_to     = (const float*)d_in[2];
    const int*   syn_x    = (const int*)d_in[3];
    const int*   syn_z    = (const int*)d_in[4];
    const int*   fi_x     = (const int*)d_in[5];
    const int*   ti_x     = (const int*)d_in[6];
    const int*   fi_z     = (const int*)d_in[7];
    const int*   ti_z     = (const int*)d_in[8];
    const float* Wx1      = (const float*)d_in[9];
    const float* Wx2      = (const float*)d_in[10];
    const float* Wz1      = (const float*)d_in[11];
    const float* Wz2      = (const float*)d_in[12];
    const float* We1      = (const float*)d_in[13];
    const float* We2      = (const float*)d_in[14];

    int* ws = (int*)d_ws;
    int* ids_x  = ws + WS_IDS_X;
    int* ids_z  = ws + WS_IDS_Z;
    int* off_x  = ws + WS_OFF_X;
    int* off_z  = ws + WS_OFF_Z;
    int* cnt_x  = ws + WS_CNT_X;
    int* cnt_z  = ws + WS_CNT_Z;
    int* cur_x  = ws + WS_CUR_X;
    int* cur_z  = ws + WS_CUR_Z;
    int* incl_x = ws + WS_INCL_X;
    int* incl_z = ws + WS_INCL_Z;
    int* psum   = ws + WS_PSUM;
    int* base   = ws + WS_BASE;
    uint4* a1x  = (uint4*)(ws + WS_A1X);
    uint4* a1z  = (uint4*)(ws + WS_A1Z);

    // cur_* are dead after fill -> reuse as syndrome bitmasks
    unsigned* bits_x = (unsigned*)cur_x;
    unsigned* bits_z = (unsigned*)cur_z;

    hipMemsetAsync(cnt_x, 0, 2 * NUM_VN * sizeof(int), stream);

    hist_kernel<<<dim3((NUM_E + 255) / 256), dim3(256), 0, stream>>>(
        ti_x, ti_z, cnt_x, cnt_z);
    scan1_kernel<<<dim3(SCAN_CHUNKS, 2), dim3(1024), 0, stream>>>(
        cnt_x, cnt_z, incl_x, incl_z, psum);
    scan2_kernel<<<dim3(1), dim3(64), 0, stream>>>(psum, base);
    scan3_kernel<<<dim3(SCAN_CHUNKS, 2), dim3(1024), 0, stream>>>(
        cnt_x, cnt_z, incl_x, incl_z, base, off_x, off_z, cur_x, cur_z);
    fill_kernel<<<dim3((NUM_E + 255) / 256), dim3(256), 0, stream>>>(
        ti_x, ti_z, fi_x, fi_z, cur_x, cur_z, ids_x, ids_z);
    pack_bits_kernel<<<dim3((NUM_CN + 255) / 256), dim3(256), 0, stream>>>(
        syn_x, syn_z, bits_x, bits_z);

    a1_kernel<<<dim3((NUM_CN * BATCH + 255) / 256, 2), dim3(256), 0, stream>>>(
        h_from_x, h_from_z, Wx1, Wz1, a1x, a1z);

    gather_kernel<<<dim3((NUM_VN * BATCH) / 256), dim3(256), 0, stream>>>(
        h_to, bits_x, bits_z, off_x, ids_x, off_z, ids_z, a1x, a1z,
        Wx1, Wx2, Wz1, Wz2, (uint4*)d_out);

    node_kernel<<<dim3((NUM_VN * BATCH) / 256), dim3(256), 0, stream>>>(
        h_to, We1, We2, (float*)d_out);
}